// Round 1
// baseline (19740.378 us; speedup 1.0000x reference)
//
#include <hip/hip_runtime.h>
#include <math.h>

// ---- problem constants ----
#define C_      3
#define H_      224
#define W_      224
#define P_      16
#define KH_     14
#define KW_     14
#define NPATCH  196
#define PELEMS  768
#define D_      768
#define HEADS_  12
#define Y_      64
#define MHID    3072
#define NMASK   100
#define NSTEPS  12
#define ALPHA_  0.1f
#define BETA_   0.125f     /* 1/sqrt(64) exact */
#define EPS_    1e-5f
#define B_      16
#define NTOK    197        /* 1 + NPATCH */
#define ROWS    (B_*NTOK)  /* 3152 */

// ---------------------------------------------------------------------------
// Wq (H,D,Y) -> Wp (D, H*Y) contiguous row-major
__global__ __launch_bounds__(256) void transpose_w_kernel(const float* __restrict__ W,
                                                          float* __restrict__ Wp)
{
    int idx = blockIdx.x * 256 + threadIdx.x;   // idx = d*768 + col
    int col = idx % D_;
    int d   = idx / D_;
    int h = col >> 6, y = col & 63;
    Wp[idx] = W[((size_t)h * D_ + d) * Y_ + y];
}

// ---------------------------------------------------------------------------
// per-sample mask flags: first 100 ones get masked; if count<100, index 0 too
__global__ void mask_flags_kernel(const int* __restrict__ mask, int* __restrict__ flags)
{
    int b = threadIdx.x;
    if (b >= B_) return;
    const int* mb = mask + b * NPATCH;
    int* fb = flags + b * NPATCH;
    int cnt = 0;
    for (int n = 0; n < NPATCH; ++n) {
        int mv = mb[n];
        fb[n] = (mv == 1 && cnt < NMASK) ? 1 : 0;
        cnt += (mv == 1);
    }
    if (cnt < NMASK) fb[0] = 1;   // fill_value=0 => tok[0] gets mask_token
}

// ---------------------------------------------------------------------------
// tok[b,n,:] = patch(b,n) @ enc_W + enc_b     (one block per (b,n) row)
__global__ __launch_bounds__(256) void encoder_kernel(const float* __restrict__ img,
                                                      const float* __restrict__ enc_W,
                                                      const float* __restrict__ enc_b,
                                                      float* __restrict__ tok)
{
    int bid = blockIdx.x;
    int b = bid / NPATCH, n = bid % NPATCH;
    int kh = n / KW_, kw = n % KW_;
    int tid = threadIdx.x;

    __shared__ float patch[PELEMS];
    for (int e = tid; e < PELEMS; e += 256) {
        int c = e >> 8, pe = e & 255, p = pe >> 4, q2 = pe & 15;
        patch[e] = img[(((size_t)b * C_ + c) * H_ + kh * 16 + p) * W_ + kw * 16 + q2];
    }
    __syncthreads();

    float acc0 = 0.f, acc1 = 0.f, acc2 = 0.f;
    for (int e = 0; e < PELEMS; ++e) {
        float pv = patch[e];
        const float* wr = enc_W + (size_t)e * D_;
        acc0 += pv * wr[tid];
        acc1 += pv * wr[tid + 256];
        acc2 += pv * wr[tid + 512];
    }
    float* tr = tok + ((size_t)b * NPATCH + n) * D_;
    tr[tid]       = acc0 + enc_b[tid];
    tr[tid + 256] = acc1 + enc_b[tid + 256];
    tr[tid + 512] = acc2 + enc_b[tid + 512];
}

// ---------------------------------------------------------------------------
// x[b,0,:] = cls + pos[0];  x[b,1+n,:] = (flag ? mask_token : tok) + pos[1+n]
__global__ __launch_bounds__(256) void build_x_kernel(const float* __restrict__ tok,
                                                      const int* __restrict__ flags,
                                                      const float* __restrict__ cls,
                                                      const float* __restrict__ mtok,
                                                      const float* __restrict__ pos,
                                                      float* __restrict__ x)
{
    int row = blockIdx.x;          // b*197 + r
    int b = row / NTOK, r = row % NTOK;
    int tid = threadIdx.x;
#pragma unroll
    for (int i = 0; i < 3; ++i) {
        int d = tid + (i << 8);
        float v;
        if (r == 0) v = cls[d];
        else {
            int n = r - 1;
            v = flags[b * NPATCH + n] ? mtok[d]
                                      : tok[((size_t)b * NPATCH + n) * D_ + d];
        }
        x[(size_t)row * D_ + d] = v + pos[(size_t)r * D_ + d];
    }
}

// ---------------------------------------------------------------------------
// layernorm rows of x -> g
__global__ __launch_bounds__(256) void lnorm_kernel(const float* __restrict__ x,
                                                    float* __restrict__ g,
                                                    const float* __restrict__ gamma,
                                                    const float* __restrict__ delta)
{
    int row = blockIdx.x, tid = threadIdx.x;
    const float* xr = x + (size_t)row * D_;
    float v0 = xr[tid], v1 = xr[tid + 256], v2 = xr[tid + 512];

    __shared__ float red[256];
    red[tid] = v0 + v1 + v2;
    __syncthreads();
    for (int off = 128; off > 0; off >>= 1) {
        if (tid < off) red[tid] += red[tid + off];
        __syncthreads();
    }
    float mean = red[0] * (1.0f / D_);
    __syncthreads();
    float a0 = v0 - mean, a1 = v1 - mean, a2 = v2 - mean;
    red[tid] = a0 * a0 + a1 * a1 + a2 * a2;
    __syncthreads();
    for (int off = 128; off > 0; off >>= 1) {
        if (tid < off) red[tid] += red[tid + off];
        __syncthreads();
    }
    float var = red[0] * (1.0f / D_);
    float inv = gamma[0] / sqrtf(var + EPS_);
    float* gr = g + (size_t)row * D_;
    gr[tid]       = a0 * inv + delta[tid];
    gr[tid + 256] = a1 * inv + delta[tid + 256];
    gr[tid + 512] = a2 * inv + delta[tid + 512];
}

// ---------------------------------------------------------------------------
// generic 64x64-tile fp32 GEMM: C = [relu]( A @ op(B) [+ bias] )  [+= if acc]
// bNT=0: B is K x N (ldb between k-rows). bNT=1: B is N x K (ldb between n-rows).
__global__ __launch_bounds__(256) void gemm_kernel(const float* __restrict__ A, int lda,
                                                   const float* __restrict__ B, int ldb,
                                                   float* __restrict__ Cm, int ldc,
                                                   int M, int N, int K,
                                                   int bNT, int accumulate, int doRelu,
                                                   const float* __restrict__ bias)
{
    __shared__ float As[16][68];   // [k][m], padded so float4 rows stay 16B-aligned
    __shared__ float Bs[16][68];   // [k][n]
    const int t  = threadIdx.x;
    const int tx = t & 15, ty = t >> 4;
    const int br = blockIdx.y << 6, bc = blockIdx.x << 6;

    float acc[4][4] = {{0.f}};

    for (int k0 = 0; k0 < K; k0 += 16) {
#pragma unroll
        for (int i = 0; i < 4; ++i) {           // A: 1024 elems / 256 thr
            int l = t + (i << 8);
            int kk = l & 15, m = l >> 4;
            int gr = br + m;
            As[kk][m] = (gr < M) ? A[(size_t)gr * lda + k0 + kk] : 0.f;
        }
        if (!bNT) {
#pragma unroll
            for (int i = 0; i < 4; ++i) {
                int l = t + (i << 8);
                int nn = l & 63, kk = l >> 6;
                Bs[kk][nn] = B[(size_t)(k0 + kk) * ldb + bc + nn];
            }
        } else {
#pragma unroll
            for (int i = 0; i < 4; ++i) {
                int l = t + (i << 8);
                int kk = l & 15, nn = l >> 4;
                Bs[kk][nn] = B[(size_t)(bc + nn) * ldb + k0 + kk];
            }
        }
        __syncthreads();
#pragma unroll
        for (int kk = 0; kk < 16; ++kk) {
            float4 av = *reinterpret_cast<const float4*>(&As[kk][ty << 2]);
            float4 bv = *reinterpret_cast<const float4*>(&Bs[kk][tx << 2]);
            float a[4] = {av.x, av.y, av.z, av.w};
            float b[4] = {bv.x, bv.y, bv.z, bv.w};
#pragma unroll
            for (int i = 0; i < 4; ++i)
#pragma unroll
                for (int j = 0; j < 4; ++j)
                    acc[i][j] += a[i] * b[j];
        }
        __syncthreads();
    }

#pragma unroll
    for (int i = 0; i < 4; ++i) {
        int r = br + (ty << 2) + i;
        if (r >= M) continue;
#pragma unroll
        for (int j = 0; j < 4; ++j) {
            int cc = bc + (tx << 2) + j;
            if (cc >= N) continue;
            float v = acc[i][j];
            if (bias) v += bias[cc];
            if (doRelu) v = fmaxf(v, 0.f);
            float* dst = &Cm[(size_t)r * ldc + cc];
            if (accumulate) *dst += v;
            else            *dst = v;
        }
    }
}

// ---------------------------------------------------------------------------
// softmax rows of beta * q k^T per (b,h,n) -> P
__global__ __launch_bounds__(256) void attn_softmax_kernel(const float* __restrict__ q,
                                                           const float* __restrict__ k,
                                                           float* __restrict__ P)
{
    int id = blockIdx.x;
    int n = id % NTOK, bh = id / NTOK;
    int h = bh % HEADS_, b = bh / HEADS_;
    int tid = threadIdx.x;

    __shared__ float qs[Y_];
    if (tid < Y_) qs[tid] = q[((size_t)(b * NTOK + n)) * D_ + h * Y_ + tid];
    __syncthreads();

    float val = -1e30f;
    if (tid < NTOK) {
        const float* kr = k + ((size_t)(b * NTOK + tid)) * D_ + h * Y_;
        float dot = 0.f;
#pragma unroll 8
        for (int yy = 0; yy < Y_; ++yy) dot += qs[yy] * kr[yy];
        val = BETA_ * dot;
    }
    __shared__ float red[256];
    red[tid] = val;
    __syncthreads();
    for (int off = 128; off > 0; off >>= 1) {
        if (tid < off) red[tid] = fmaxf(red[tid], red[tid + off]);
        __syncthreads();
    }
    float mx = red[0];
    __syncthreads();
    float p = (tid < NTOK) ? expf(val - mx) : 0.f;
    red[tid] = p;
    __syncthreads();
    for (int off = 128; off > 0; off >>= 1) {
        if (tid < off) red[tid] += red[tid + off];
        __syncthreads();
    }
    float inv = 1.0f / red[0];
    if (tid < NTOK)
        P[((size_t)bh * NTOK + n) * NTOK + tid] = p * inv;
}

// ---------------------------------------------------------------------------
// Gq[n,h,:] = P[h,n,:] @ k[:,h,:]    (one wave per (b,h,n))
__global__ __launch_bounds__(64) void attn_gq_kernel(const float* __restrict__ P,
                                                     const float* __restrict__ k,
                                                     float* __restrict__ Gq)
{
    int id = blockIdx.x;
    int n = id % NTOK, bh = id / NTOK;
    int h = bh % HEADS_, b = bh / HEADS_;
    int y = threadIdx.x;

    __shared__ float Ps[NTOK];
    const float* Prow = P + ((size_t)bh * NTOK + n) * NTOK;
    for (int m = y; m < NTOK; m += 64) Ps[m] = Prow[m];
    __syncthreads();

    const float* kb = k + (size_t)(b * NTOK) * D_ + h * Y_ + y;
    float acc = 0.f;
    for (int m = 0; m < NTOK; ++m) acc += Ps[m] * kb[(size_t)m * D_];
    Gq[((size_t)(b * NTOK + n)) * D_ + h * Y_ + y] = acc;
}

// Gk[m,h,:] = P[h,:,m]^T @ q[:,h,:]  (one wave per (b,h,m))
__global__ __launch_bounds__(64) void attn_gk_kernel(const float* __restrict__ P,
                                                     const float* __restrict__ q,
                                                     float* __restrict__ Gk)
{
    int id = blockIdx.x;
    int m = id % NTOK, bh = id / NTOK;
    int h = bh % HEADS_, b = bh / HEADS_;
    int y = threadIdx.x;

    __shared__ float Ps[NTOK];
    for (int nn = y; nn < NTOK; nn += 64)
        Ps[nn] = P[((size_t)bh * NTOK + nn) * NTOK + m];
    __syncthreads();

    const float* qb = q + (size_t)(b * NTOK) * D_ + h * Y_ + y;
    float acc = 0.f;
    for (int nn = 0; nn < NTOK; ++nn) acc += Ps[nn] * qb[(size_t)nn * D_];
    Gk[((size_t)(b * NTOK + m)) * D_ + h * Y_ + y] = acc;
}

// ---------------------------------------------------------------------------
__global__ __launch_bounds__(256) void update_x_kernel(float* __restrict__ x,
                                                       const float* __restrict__ grad)
{
    int i = blockIdx.x * 256 + threadIdx.x;
    x[i] += ALPHA_ * grad[i];
}

// ---------------------------------------------------------------------------
// out[b,c,kh*16+p,kw*16+q] = dec[b*197+1+(kh*14+kw), c*256+p*16+q]
__global__ __launch_bounds__(256) void unpatch_kernel(const float* __restrict__ dec,
                                                      float* __restrict__ out)
{
    int idx = blockIdx.x * 256 + threadIdx.x;
    int ww = idx % W_;
    int t2 = idx / W_;
    int hh = t2 % H_;
    int t3 = t2 / H_;
    int c  = t3 % C_;
    int b  = t3 / C_;
    int kh = hh >> 4, p = hh & 15, kw = ww >> 4, q2 = ww & 15;
    int n = kh * KW_ + kw;
    int e = (c << 8) + (p << 4) + q2;
    out[idx] = dec[((size_t)b * NTOK + 1 + n) * D_ + e];
}

// ---------------------------------------------------------------------------
extern "C" void kernel_launch(void* const* d_in, const int* in_sizes, int n_in,
                              void* d_out, int out_size, void* d_ws, size_t ws_size,
                              hipStream_t stream)
{
    const float* img   = (const float*)d_in[0];
    const int*   mask  = (const int*)d_in[1];
    const float* enc_W = (const float*)d_in[2];
    const float* enc_b = (const float*)d_in[3];
    const float* dec_W = (const float*)d_in[4];
    const float* dec_b = (const float*)d_in[5];
    const float* cls   = (const float*)d_in[6];
    const float* mtok  = (const float*)d_in[7];
    const float* pos   = (const float*)d_in[8];
    const float* Wq    = (const float*)d_in[9];
    const float* Wk    = (const float*)d_in[10];
    const float* Xi    = (const float*)d_in[11];
    const float* gamma = (const float*)d_in[12];
    const float* delta = (const float*)d_in[13];
    float* out = (float*)d_out;

    // workspace layout (~121 MB)
    float* ws = (float*)d_ws;
    size_t off = 0;
    auto alloc = [&](size_t n) { float* p = ws + off; off += n; return p; };
    float* x    = alloc((size_t)ROWS * D_);
    float* g    = alloc((size_t)ROWS * D_);
    float* qb   = alloc((size_t)ROWS * D_);
    float* kb   = alloc((size_t)ROWS * D_);
    float* grad = alloc((size_t)ROWS * D_);
    float* Gq   = alloc((size_t)ROWS * D_);
    float* Gk   = alloc((size_t)ROWS * D_);
    float* U    = alloc((size_t)ROWS * MHID);     // union: P (attn probs) then hid
    float* tok  = alloc((size_t)B_ * NPATCH * D_);
    float* Wqp  = alloc((size_t)D_ * D_);
    float* Wkp  = alloc((size_t)D_ * D_);
    int*   flags = (int*)(ws + off);

    // ---- pre-pack weights, mask flags, encode, build x ----
    transpose_w_kernel<<<dim3(D_ * D_ / 256), dim3(256), 0, stream>>>(Wq, Wqp);
    transpose_w_kernel<<<dim3(D_ * D_ / 256), dim3(256), 0, stream>>>(Wk, Wkp);
    mask_flags_kernel<<<dim3(1), dim3(64), 0, stream>>>(mask, flags);
    encoder_kernel<<<dim3(B_ * NPATCH), dim3(256), 0, stream>>>(img, enc_W, enc_b, tok);
    build_x_kernel<<<dim3(ROWS), dim3(256), 0, stream>>>(tok, flags, cls, mtok, pos, x);

    const dim3 blk(256);
    const int gy = (ROWS + 63) / 64;          // 50
    for (int step = 0; step < NSTEPS; ++step) {
        lnorm_kernel<<<dim3(ROWS), blk, 0, stream>>>(x, g, gamma, delta);
        // q = g @ Wq',  k = g @ Wk'
        gemm_kernel<<<dim3(D_ / 64, gy), blk, 0, stream>>>(g, D_, Wqp, D_, qb, D_,
                                                           ROWS, D_, D_, 0, 0, 0, nullptr);
        gemm_kernel<<<dim3(D_ / 64, gy), blk, 0, stream>>>(g, D_, Wkp, D_, kb, D_,
                                                           ROWS, D_, D_, 0, 0, 0, nullptr);
        // P = softmax(beta q k^T) per (b,h)
        attn_softmax_kernel<<<dim3(B_ * HEADS_ * NTOK), blk, 0, stream>>>(qb, kb, U);
        attn_gq_kernel<<<dim3(B_ * HEADS_ * NTOK), dim3(64), 0, stream>>>(U, kb, Gq);
        attn_gk_kernel<<<dim3(B_ * HEADS_ * NTOK), dim3(64), 0, stream>>>(U, qb, Gk);
        // hid = relu(g @ Xi)   (overwrites U: P is dead now)
        gemm_kernel<<<dim3(MHID / 64, gy), blk, 0, stream>>>(g, D_, Xi, MHID, U, MHID,
                                                             ROWS, MHID, D_, 0, 0, 1, nullptr);
        // grad = hid @ Xi^T
        gemm_kernel<<<dim3(D_ / 64, gy), blk, 0, stream>>>(U, MHID, Xi, MHID, grad, D_,
                                                           ROWS, D_, MHID, 1, 0, 0, nullptr);
        // grad += Gq @ Wq'^T ; grad += Gk @ Wk'^T
        gemm_kernel<<<dim3(D_ / 64, gy), blk, 0, stream>>>(Gq, D_, Wqp, D_, grad, D_,
                                                           ROWS, D_, D_, 1, 1, 0, nullptr);
        gemm_kernel<<<dim3(D_ / 64, gy), blk, 0, stream>>>(Gk, D_, Wkp, D_, grad, D_,
                                                           ROWS, D_, D_, 1, 1, 0, nullptr);
        // x += alpha * grad
        update_x_kernel<<<dim3(ROWS * D_ / 256), blk, 0, stream>>>(x, grad);
    }

    // final layernorm + decode + unpatchify (dec result reuses qb)
    lnorm_kernel<<<dim3(ROWS), blk, 0, stream>>>(x, g, gamma, delta);
    gemm_kernel<<<dim3(D_ / 64, gy), blk, 0, stream>>>(g, D_, dec_W, D_, qb, D_,
                                                       ROWS, D_, D_, 0, 0, 0, dec_b);
    unpatch_kernel<<<dim3(B_ * C_ * H_ * W_ / 256), blk, 0, stream>>>(qb, out);
}

// Round 3
// 7806.782 us; speedup vs baseline: 2.5286x; 2.5286x over previous
//
#include <hip/hip_runtime.h>
#include <math.h>

// ---- problem constants ----
#define C_      3
#define H_      224
#define W_      224
#define KH_     14
#define KW_     14
#define NPATCH  196
#define PELEMS  768
#define D_      768
#define HEADS_  12
#define Y_      64
#define MHID    3072
#define NMASK   100
#define NSTEPS  12
#define ALPHA_  0.1f
#define BETA_   0.125f
#define EPS_    1e-5f
#define B_      16
#define NTOK    197
#define ROWS    (B_*NTOK)   /* 3152 real rows */
#define MPAD    3200        /* 25 * 128 */
#define QKLD    1536        /* fused q|k leading dim */
#define PACKLD  4608        /* hid(3072) | Gq(768) | Gk(768) */

typedef short short8 __attribute__((ext_vector_type(8)));
typedef float floatx4 __attribute__((ext_vector_type(4)));

__device__ __forceinline__ unsigned short f2bf(float f) {
    union { float f; unsigned u; } v; v.f = f;
    unsigned r = (v.u + 0x7FFFu + ((v.u >> 16) & 1u)) >> 16;
    return (unsigned short)r;
}

__device__ __forceinline__ void async_cp16(const void* g, void* l) {
    __builtin_amdgcn_global_load_lds(
        (const __attribute__((address_space(1))) unsigned int*)g,
        (__attribute__((address_space(3))) unsigned int*)l, 16, 0, 0);
}

// ---------------------------------------------------------------------------
// MFMA bf16 NT GEMM: C[M=grid.y*128][N=grid.x*128] = A(MxK bf16) @ B(NxK bf16)^T
// m97 structure: 128x128 tile, BK=32, global_load_lds width 16.
template<int OUT_BF16, bool RELU, bool HAS_BIAS>
__global__ __launch_bounds__(256) void mfma_gemm(
    const unsigned short* __restrict__ A, int lda,
    const unsigned short* __restrict__ B, int ldb,
    void* __restrict__ Cout, int ldc,
    const float* __restrict__ bias, int K)
{
    __shared__ alignas(16) unsigned short ldsA[128 * 32];
    __shared__ alignas(16) unsigned short ldsB[128 * 32];
    const int t    = threadIdx.x;
    const int wave = t >> 6;
    const int lane = t & 63;
    const int row0 = blockIdx.y << 7;
    const int col0 = blockIdx.x << 7;
    const int wm = (wave & 1) << 6;
    const int wn = (wave >> 1) << 6;
    const int r  = lane & 15;
    const int qd = lane >> 4;

    const unsigned short* Abase = A + (size_t)row0 * lda;
    const unsigned short* Bbase = B + (size_t)col0 * ldb;

    floatx4 acc[4][4];
#pragma unroll
    for (int i = 0; i < 4; ++i)
#pragma unroll
        for (int j = 0; j < 4; ++j)
            acc[i][j] = (floatx4){0.f, 0.f, 0.f, 0.f};

    // staging decomposition: chunk c in [0,512) covers 16B; row=c>>2, off=(c&3)*8
    const int c0   = t;            // first chunk
    const int row_a0 = c0 >> 2, off_a0 = (c0 & 3) << 3;
    const int c1   = t + 256;      // second chunk
    const int row_a1 = c1 >> 2, off_a1 = (c1 & 3) << 3;
    // wave-uniform LDS dest bases (shorts): chunk c -> byte c*16
    unsigned short* ldA0 = ldsA + (wave << 9);
    unsigned short* ldA1 = ldsA + 2048 + (wave << 9);
    unsigned short* ldB0 = ldsB + (wave << 9);
    unsigned short* ldB1 = ldsB + 2048 + (wave << 9);

    for (int k0 = 0; k0 < K; k0 += 32) {
        async_cp16(Abase + (size_t)row_a0 * lda + k0 + off_a0, ldA0);
        async_cp16(Abase + (size_t)row_a1 * lda + k0 + off_a1, ldA1);
        async_cp16(Bbase + (size_t)row_a0 * ldb + k0 + off_a0, ldB0);
        async_cp16(Bbase + (size_t)row_a1 * ldb + k0 + off_a1, ldB1);
        __syncthreads();

        short8 af[4], bfr[4];
#pragma unroll
        for (int i = 0; i < 4; ++i) {
            af[i]  = *(const short8*)&ldsA[(wm + (i << 4) + r) * 32 + (qd << 3)];
            bfr[i] = *(const short8*)&ldsB[(wn + (i << 4) + r) * 32 + (qd << 3)];
        }
#pragma unroll
        for (int i = 0; i < 4; ++i)
#pragma unroll
            for (int j = 0; j < 4; ++j)
                acc[i][j] = __builtin_amdgcn_mfma_f32_16x16x32_bf16(
                                af[i], bfr[j], acc[i][j], 0, 0, 0);
        __syncthreads();
    }

#pragma unroll
    for (int i = 0; i < 4; ++i) {
#pragma unroll
        for (int j = 0; j < 4; ++j) {
            int cc = col0 + wn + (j << 4) + r;
#pragma unroll
            for (int reg = 0; reg < 4; ++reg) {
                int rr = row0 + wm + (i << 4) + (qd << 2) + reg;
                float v = acc[i][j][reg];
                if (HAS_BIAS) v += bias[cc];
                if (RELU)     v = fmaxf(v, 0.f);
                if (OUT_BF16) ((unsigned short*)Cout)[(size_t)rr * ldc + cc] = f2bf(v);
                else          ((float*)Cout)[(size_t)rr * ldc + cc] = v;
            }
        }
    }
}

// ---------------------------------------------------------------------------
// setup conversions
// WqkT[c][d], c in [0,1536): c<768 -> Wq[h=c>>6][d][y=c&63]; else Wk[(c-768)...]
__global__ __launch_bounds__(256) void wqkt_kernel(const float* __restrict__ Wq,
                                                   const float* __restrict__ Wk,
                                                   unsigned short* __restrict__ out)
{
    int idx = blockIdx.x * 256 + threadIdx.x;          // c*768 + d
    int d = idx % D_, c = idx / D_;
    const float* W = (c < 768) ? Wq : Wk;
    int cc = (c < 768) ? c : c - 768;                  // FIX: 768 is not pow2
    out[idx] = f2bf(W[((size_t)(cc >> 6) * D_ + d) * Y_ + (cc & 63)]);
}

// Bpack[d][c], c in [0,4608): c<3072 -> Xi[d][c]; c<3840 -> Wq[h][d][y]; else Wk
__global__ __launch_bounds__(256) void bpack_kernel(const float* __restrict__ Xi,
                                                    const float* __restrict__ Wq,
                                                    const float* __restrict__ Wk,
                                                    unsigned short* __restrict__ out)
{
    int idx = blockIdx.x * 256 + threadIdx.x;          // d*4608 + c
    int c = idx % PACKLD, d = idx / PACKLD;
    float v;
    if (c < 3072)       v = Xi[(size_t)d * MHID + c];
    else if (c < 3840)  { int e = c - 3072; v = Wq[((size_t)(e >> 6) * D_ + d) * Y_ + (e & 63)]; }
    else                { int e = c - 3840; v = Wk[((size_t)(e >> 6) * D_ + d) * Y_ + (e & 63)]; }
    out[idx] = f2bf(v);
}

// XiT[m][d] = Xi[d][m]
__global__ __launch_bounds__(256) void xit_kernel(const float* __restrict__ Xi,
                                                  unsigned short* __restrict__ out)
{
    int idx = blockIdx.x * 256 + threadIdx.x;          // m*768 + d
    int d = idx % D_, m = idx / D_;
    out[idx] = f2bf(Xi[(size_t)d * MHID + m]);
}

// generic 768x768 transpose to bf16: out[n][k] = in[k][n]
__global__ __launch_bounds__(256) void t768_kernel(const float* __restrict__ in,
                                                   unsigned short* __restrict__ out)
{
    int idx = blockIdx.x * 256 + threadIdx.x;          // n*768 + k
    int k = idx % D_, n = idx / D_;
    out[idx] = f2bf(in[(size_t)k * D_ + n]);
}

// ---------------------------------------------------------------------------
__global__ void mask_flags_kernel(const int* __restrict__ mask, int* __restrict__ flags)
{
    int b = threadIdx.x;
    if (b >= B_) return;
    const int* mb = mask + b * NPATCH;
    int* fb = flags + b * NPATCH;
    int cnt = 0;
    for (int n = 0; n < NPATCH; ++n) {
        int mv = mb[n];
        fb[n] = (mv == 1 && cnt < NMASK) ? 1 : 0;
        cnt += (mv == 1);
    }
    if (cnt < NMASK) fb[0] = 1;
}

// patch[b*196+n][e] bf16
__global__ __launch_bounds__(256) void patchify_kernel(const float* __restrict__ img,
                                                       unsigned short* __restrict__ patch)
{
    int idx = blockIdx.x * 256 + threadIdx.x;          // row*768 + e
    int e = idx % PELEMS, row = idx / PELEMS;
    int b = row / NPATCH, n = row % NPATCH;
    int kh = n / KW_, kw = n % KW_;
    int c = e >> 8, p = (e >> 4) & 15, q2 = e & 15;
    patch[idx] = f2bf(img[(((size_t)b * C_ + c) * H_ + kh * 16 + p) * W_ + kw * 16 + q2]);
}

// x[b,0,:]=cls+pos[0]; x[b,1+n,:]= (flag?mask_token:tok)+pos[1+n]
__global__ __launch_bounds__(256) void build_x_kernel(const float* __restrict__ tok,
                                                      const int* __restrict__ flags,
                                                      const float* __restrict__ cls,
                                                      const float* __restrict__ mtok,
                                                      const float* __restrict__ pos,
                                                      float* __restrict__ x)
{
    int row = blockIdx.x;
    int b = row / NTOK, rr = row % NTOK;
    int tid = threadIdx.x;
#pragma unroll
    for (int i = 0; i < 3; ++i) {
        int d = tid + (i << 8);
        float v;
        if (rr == 0) v = cls[d];
        else {
            int n = rr - 1;
            v = flags[b * NPATCH + n] ? mtok[d]
                                      : tok[((size_t)b * NPATCH + n) * D_ + d];
        }
        x[(size_t)row * D_ + d] = v + pos[(size_t)rr * D_ + d];
    }
}

// layernorm rows of x -> g (bf16)
__global__ __launch_bounds__(256) void lnorm_kernel(const float* __restrict__ x,
                                                    unsigned short* __restrict__ g,
                                                    const float* __restrict__ gamma,
                                                    const float* __restrict__ delta)
{
    int row = blockIdx.x, tid = threadIdx.x;
    const float* xr = x + (size_t)row * D_;
    float v0 = xr[tid], v1 = xr[tid + 256], v2 = xr[tid + 512];

    __shared__ float red[256];
    red[tid] = v0 + v1 + v2;
    __syncthreads();
    for (int off = 128; off > 0; off >>= 1) {
        if (tid < off) red[tid] += red[tid + off];
        __syncthreads();
    }
    float mean = red[0] * (1.0f / D_);
    __syncthreads();
    float a0 = v0 - mean, a1 = v1 - mean, a2 = v2 - mean;
    red[tid] = a0 * a0 + a1 * a1 + a2 * a2;
    __syncthreads();
    for (int off = 128; off > 0; off >>= 1) {
        if (tid < off) red[tid] += red[tid + off];
        __syncthreads();
    }
    float var = red[0] * (1.0f / D_);
    float inv = gamma[0] / sqrtf(var + EPS_);
    unsigned short* gr = g + (size_t)row * D_;
    gr[tid]       = f2bf(a0 * inv + delta[tid]);
    gr[tid + 256] = f2bf(a1 * inv + delta[tid + 256]);
    gr[tid + 512] = f2bf(a2 * inv + delta[tid + 512]);
}

// ---------------------------------------------------------------------------
// softmax rows of beta * q k^T per (b,h,n) -> P   (q,k inside fused qk buffer)
__global__ __launch_bounds__(256) void attn_softmax_kernel(const float* __restrict__ qk,
                                                           float* __restrict__ P)
{
    int id = blockIdx.x;
    int n = id % NTOK, bh = id / NTOK;
    int h = bh % HEADS_, b = bh / HEADS_;
    int tid = threadIdx.x;

    __shared__ float qs[Y_];
    if (tid < Y_) qs[tid] = qk[(size_t)(b * NTOK + n) * QKLD + h * Y_ + tid];
    __syncthreads();

    float val = -1e30f;
    if (tid < NTOK) {
        const float* kr = qk + (size_t)(b * NTOK + tid) * QKLD + 768 + h * Y_;
        float dot = 0.f;
#pragma unroll 8
        for (int yy = 0; yy < Y_; ++yy) dot += qs[yy] * kr[yy];
        val = BETA_ * dot;
    }
    __shared__ float red[256];
    red[tid] = val;
    __syncthreads();
    for (int off = 128; off > 0; off >>= 1) {
        if (tid < off) red[tid] = fmaxf(red[tid], red[tid + off]);
        __syncthreads();
    }
    float mx = red[0];
    __syncthreads();
    float p = (tid < NTOK) ? expf(val - mx) : 0.f;
    red[tid] = p;
    __syncthreads();
    for (int off = 128; off > 0; off >>= 1) {
        if (tid < off) red[tid] += red[tid + off];
        __syncthreads();
    }
    float inv = 1.0f / red[0];
    if (tid < NTOK)
        P[((size_t)bh * NTOK + n) * NTOK + tid] = p * inv;
}

// Gq[n,h*64+y] = sum_m P[h,n,m] k[m,h,y]  -> bf16 into packed buffer col 3072+
__global__ __launch_bounds__(64) void attn_gq_kernel(const float* __restrict__ P,
                                                     const float* __restrict__ qk,
                                                     unsigned short* __restrict__ pack)
{
    int id = blockIdx.x;
    int n = id % NTOK, bh = id / NTOK;
    int h = bh % HEADS_, b = bh / HEADS_;
    int y = threadIdx.x;

    __shared__ float Ps[NTOK];
    const float* Prow = P + ((size_t)bh * NTOK + n) * NTOK;
    for (int m = y; m < NTOK; m += 64) Ps[m] = Prow[m];
    __syncthreads();

    const float* kb = qk + (size_t)(b * NTOK) * QKLD + 768 + h * Y_ + y;
    float acc = 0.f;
    for (int m = 0; m < NTOK; ++m) acc += Ps[m] * kb[(size_t)m * QKLD];
    pack[(size_t)(b * NTOK + n) * PACKLD + 3072 + h * Y_ + y] = f2bf(acc);
}

// Gk[m,h*64+y] = sum_n P[h,n,m] q[n,h,y]  -> bf16 into packed buffer col 3840+
__global__ __launch_bounds__(64) void attn_gk_kernel(const float* __restrict__ P,
                                                     const float* __restrict__ qk,
                                                     unsigned short* __restrict__ pack)
{
    int id = blockIdx.x;
    int m = id % NTOK, bh = id / NTOK;
    int h = bh % HEADS_, b = bh / HEADS_;
    int y = threadIdx.x;

    __shared__ float Ps[NTOK];
    for (int nn = y; nn < NTOK; nn += 64)
        Ps[nn] = P[((size_t)bh * NTOK + nn) * NTOK + m];
    __syncthreads();

    const float* qb = qk + (size_t)(b * NTOK) * QKLD + h * Y_ + y;
    float acc = 0.f;
    for (int nn = 0; nn < NTOK; ++nn) acc += Ps[nn] * qb[(size_t)nn * QKLD];
    pack[(size_t)(b * NTOK + m) * PACKLD + 3840 + h * Y_ + y] = f2bf(acc);
}

// ---------------------------------------------------------------------------
__global__ __launch_bounds__(256) void update_x_kernel(float* __restrict__ x,
                                                       const float* __restrict__ grad)
{
    int i = blockIdx.x * 256 + threadIdx.x;
    x[i] += ALPHA_ * grad[i];
}

__global__ __launch_bounds__(256) void unpatch_kernel(const float* __restrict__ dec,
                                                      float* __restrict__ out)
{
    int idx = blockIdx.x * 256 + threadIdx.x;
    int ww = idx % W_;
    int t2 = idx / W_;
    int hh = t2 % H_;
    int t3 = t2 / H_;
    int c  = t3 % C_;
    int b  = t3 / C_;
    int kh = hh >> 4, p = hh & 15, kw = ww >> 4, q2 = ww & 15;
    int n = kh * KW_ + kw;
    int e = (c << 8) + (p << 4) + q2;
    out[idx] = dec[((size_t)b * NTOK + 1 + n) * D_ + e];
}

// ---------------------------------------------------------------------------
extern "C" void kernel_launch(void* const* d_in, const int* in_sizes, int n_in,
                              void* d_out, int out_size, void* d_ws, size_t ws_size,
                              hipStream_t stream)
{
    const float* img   = (const float*)d_in[0];
    const int*   mask  = (const int*)d_in[1];
    const float* enc_W = (const float*)d_in[2];
    const float* enc_b = (const float*)d_in[3];
    const float* dec_W = (const float*)d_in[4];
    const float* dec_b = (const float*)d_in[5];
    const float* cls   = (const float*)d_in[6];
    const float* mtok  = (const float*)d_in[7];
    const float* pos   = (const float*)d_in[8];
    const float* Wq    = (const float*)d_in[9];
    const float* Wk    = (const float*)d_in[10];
    const float* Xi    = (const float*)d_in[11];
    const float* gamma = (const float*)d_in[12];
    const float* delta = (const float*)d_in[13];
    float* out = (float*)d_out;

    float* ws = (float*)d_ws;
    size_t off = 0;
    auto alloc = [&](size_t nfloats) {
        off = (off + 63) & ~(size_t)63;
        float* p = ws + off; off += nfloats; return p;
    };
    float*          x    = alloc((size_t)MPAD * D_);            // fp32
    unsigned short* g    = (unsigned short*)alloc((size_t)MPAD * D_ / 2);
    float*          qkg  = alloc((size_t)MPAD * QKLD);          // qk fp32, later grad fp32 / dec fp32
    unsigned short* pack = (unsigned short*)alloc((size_t)MPAD * PACKLD / 2); // hid|Gq|Gk bf16
    float*          P    = alloc((size_t)B_ * HEADS_ * NTOK * NTOK);
    unsigned short* WqkT = (unsigned short*)alloc((size_t)QKLD * D_ / 2);
    unsigned short* Bpk  = (unsigned short*)alloc((size_t)D_ * PACKLD / 2);
    unsigned short* XiT  = (unsigned short*)alloc((size_t)MHID * D_ / 2);
    unsigned short* decT = (unsigned short*)alloc((size_t)D_ * D_ / 2);
    unsigned short* encT = (unsigned short*)alloc((size_t)D_ * D_ / 2);
    int*            flags = (int*)alloc(B_ * NPATCH);
    // setup-phase overlays inside pack (dead until first hid GEMM)
    unsigned short* patch = pack;                                // MPAD x 768 bf16
    float*          tok   = (float*)(pack + (size_t)MPAD * D_);  // MPAD x 768 fp32

    const dim3 blk(256);

    // ---- one-time packs ----
    wqkt_kernel<<<dim3(QKLD * D_ / 256), blk, 0, stream>>>(Wq, Wk, WqkT);
    bpack_kernel<<<dim3(D_ * PACKLD / 256), blk, 0, stream>>>(Xi, Wq, Wk, Bpk);
    xit_kernel<<<dim3(MHID * D_ / 256), blk, 0, stream>>>(Xi, XiT);
    t768_kernel<<<dim3(D_ * D_ / 256), blk, 0, stream>>>(dec_W, decT);
    t768_kernel<<<dim3(D_ * D_ / 256), blk, 0, stream>>>(enc_W, encT);
    mask_flags_kernel<<<dim3(1), dim3(64), 0, stream>>>(mask, flags);

    // ---- encode + build x ----
    patchify_kernel<<<dim3(B_ * NPATCH * PELEMS / 256), blk, 0, stream>>>(img, patch);
    mfma_gemm<0, false, true><<<dim3(D_ / 128, MPAD / 128), blk, 0, stream>>>(
        patch, PELEMS, encT, PELEMS, tok, D_, enc_b, PELEMS);
    build_x_kernel<<<dim3(ROWS), blk, 0, stream>>>(tok, flags, cls, mtok, pos, x);

    // ---- energy-descent loop ----
    for (int step = 0; step < NSTEPS; ++step) {
        lnorm_kernel<<<dim3(ROWS), blk, 0, stream>>>(x, g, gamma, delta);
        // qk = g @ [Wq|Wk]   (fp32 out)
        mfma_gemm<0, false, false><<<dim3(QKLD / 128, MPAD / 128), blk, 0, stream>>>(
            g, D_, WqkT, D_, qkg, QKLD, nullptr, D_);
        // attention: P, then Gq/Gk into packed bf16 buffer
        attn_softmax_kernel<<<dim3(B_ * HEADS_ * NTOK), blk, 0, stream>>>(qkg, P);
        attn_gq_kernel<<<dim3(B_ * HEADS_ * NTOK), dim3(64), 0, stream>>>(P, qkg, pack);
        attn_gk_kernel<<<dim3(B_ * HEADS_ * NTOK), dim3(64), 0, stream>>>(P, qkg, pack);
        // hid = relu(g @ Xi)  (bf16 into packed cols 0..3071)
        mfma_gemm<1, true, false><<<dim3(MHID / 128, MPAD / 128), blk, 0, stream>>>(
            g, D_, XiT, D_, pack, PACKLD, nullptr, D_);
        // grad = [hid|Gq|Gk] @ [Xi|Wq|Wk]^T   (fp32, overlays qk which is dead)
        mfma_gemm<0, false, false><<<dim3(D_ / 128, MPAD / 128), blk, 0, stream>>>(
            pack, PACKLD, Bpk, PACKLD, qkg, D_, nullptr, PACKLD);
        update_x_kernel<<<dim3(ROWS * D_ / 256), blk, 0, stream>>>(x, qkg);
    }

    // ---- decode + unpatchify ----
    lnorm_kernel<<<dim3(ROWS), blk, 0, stream>>>(x, g, gamma, delta);
    mfma_gemm<0, false, true><<<dim3(D_ / 128, MPAD / 128), blk, 0, stream>>>(
        g, D_, decT, D_, qkg, D_, dec_b, D_);
    unpatch_kernel<<<dim3(B_ * C_ * H_ * W_ / 256), blk, 0, stream>>>(qkg, out);
}